// Round 14
// baseline (184.996 us; speedup 1.0000x reference)
//
#include <hip/hip_runtime.h>
#include <hip/hip_bf16.h>
#include <cstdint>
#include <cstddef>

// LSTMCell: gates = [input|hx] @ [Wih|Whh]^T + b_ih + b_hh  (4096 x 4096 x K=2048)
// Round 14: no-LDS no-barrier register GEMM (R13 structure) with FAT wave tiles:
// 4 waves/block (256 thr), 1 wave/SIMD (512-reg budget), wave = 128 rows x 128
// gate-cols, acc[8][8] (256 f32, AGPR side). FLOP/B = 64 > 53 -> compute-bound:
// TA ~1024 cyc/step < MFMA ~1242 cyc/step. Loads 64 KB/CU/step (was 96).
//
// A layout: [mi(16)][wm(2)][kt(64)][m(8)][lane(64)][8 u16]   (same as R13)
// W layout: [hq(16)][wn(2)][kt(64)][n(8)][lane(64)][8 u16]   n = g*2+hh
// lane = fk*16+fr: A row=...+fr, k = kt*32+fk*8..+8 (verified 16x16x32 mapping).

#define B_ROWS 4096
#define HDIM   1024
#define KDIM   2048
#define BM     256
#define T_STEPS 64

typedef unsigned short u16;
using f32x4  = __attribute__((ext_vector_type(4))) float;
using short8 = __attribute__((ext_vector_type(8))) short;
using half8  = __attribute__((ext_vector_type(8))) _Float16;

__device__ __forceinline__ u16 f2h_bits(float f) {
    _Float16 h = (_Float16)f;                    // v_cvt_f16_f32, RTN
    return __builtin_bit_cast(u16, h);
}

// ---------------- pack: f32 -> f16 fragment-major ----------------
__global__ void pack_kernel(const float* __restrict__ input, const float* __restrict__ hx,
                            const float* __restrict__ wih, const float* __restrict__ whh,
                            u16* __restrict__ Ap, u16* __restrict__ Wp)
{
    const int NA = 16 * 2 * 64 * 8 * 64;   // 1,048,576 16B-groups
    const int NW = 16 * 2 * 64 * 8 * 64;   // 1,048,576
    int stride = gridDim.x * blockDim.x;
    for (int i = blockIdx.x * blockDim.x + threadIdx.x; i < NA + NW; i += stride) {
        int isW = (i >= NA) ? 1 : 0;
        int e = isW ? i - NA : i;
        int lane = e & 63;
        int fr = lane & 15, fk = lane >> 4;
        int kt = (e >> 9) & 63;
        int k  = kt * 32 + fk * 8;
        int row;
        if (isW) {
            int nn  = (e >> 6) & 7;          // n-frag = g*2+hh
            int wnn = (e >> 15) & 1;
            int hqq = e >> 16;
            row = (nn >> 1) * 1024 + hqq * 64 + wnn * 32 + (nn & 1) * 16 + fr;
        } else {
            int m   = (e >> 6) & 7;
            int wmm = (e >> 15) & 1;
            int mii = e >> 16;
            row = mii * 256 + wmm * 128 + m * 16 + fr;
        }
        const float* s0 = isW ? wih : input;
        const float* s1 = isW ? whh : hx;
        const float* src = (k < 1024) ? (s0 + (size_t)row * 1024 + k)
                                      : (s1 + (size_t)row * 1024 + (k - 1024));
        float4 v0 = *(const float4*)src;
        float4 v1 = *(const float4*)(src + 4);
        u16* dst = (isW ? Wp : Ap) + (size_t)e * 8;
        *(ushort4*)dst = make_ushort4(f2h_bits(v0.x), f2h_bits(v0.y),
                                      f2h_bits(v0.z), f2h_bits(v0.w));
        *(ushort4*)(dst + 4) = make_ushort4(f2h_bits(v1.x), f2h_bits(v1.y),
                                            f2h_bits(v1.z), f2h_bits(v1.w));
    }
}

// ---------------- fused GEMM + LSTM epilogue (no LDS, no barriers) ----------------
__device__ __forceinline__ float sigmf(float x) { return 1.0f / (1.0f + __expf(-x)); }
__device__ __forceinline__ float tanhfast(float x) { return 1.0f - 2.0f / (1.0f + __expf(2.0f * x)); }

__launch_bounds__(256, 1)
__global__ void lstm_fused(const u16* __restrict__ Ap, const u16* __restrict__ Wp,
                           const float* __restrict__ cx, const float* __restrict__ eps_c,
                           const float* __restrict__ eps_h,
                           const float* __restrict__ bias_ih, const float* __restrict__ bias_hh,
                           const float* __restrict__ noise_q, const float* __restrict__ noise_e,
                           float* __restrict__ out)
{
    int bid = blockIdx.x;
    // XCD-bijective swizzle: XCD x gets w in [32x,32x+32) -> 2 hq values
    // (W slice 2 MB packed, L2-resident) x all 16 A panels (L3-resident).
    int w = (bid & 7) * 32 + (bid >> 3);
    int mi = w & 15;          // 16 M-chunks of 256 rows
    int hq = w >> 4;          // 16 h-chunks of 64 cols (x4 gates)
    int bm0 = mi * BM;
    int h0 = hq * 64;

    int tid  = threadIdx.x;
    int lane = tid & 63;
    int wid  = tid >> 6;      // 0..3 (1 wave per SIMD)
    int wm   = wid >> 1;      // M half (128 rows)
    int wn   = wid & 1;       // h half (32 cols x 4 gates = 128 gate-cols)
    int fr   = lane & 15, fk = lane >> 4;

    // fragment base pointers (u16 units); panel = 64kt*8frag*64lane*8 = 262144 u16
    const u16* pA = Ap + (size_t)(mi * 2 + wm) * 262144 + lane * 8;
    const u16* pW = Wp + (size_t)(hq * 2 + wn) * 262144 + lane * 8;

#define LD8(p) __builtin_bit_cast(half8, *(const short8*)(p))

#define LOADF(AA, WW, kt) do { \
        _Pragma("unroll") \
        for (int m = 0; m < 8; ++m) AA[m] = LD8(pA + (size_t)(kt) * 4096 + m * 512); \
        _Pragma("unroll") \
        for (int n = 0; n < 8; ++n) WW[n] = LD8(pW + (size_t)(kt) * 4096 + n * 512); \
    } while (0)

#define DOMFMA(AA, WW) do { \
        __builtin_amdgcn_s_setprio(1); \
        _Pragma("unroll") \
        for (int n = 0; n < 8; ++n) \
            _Pragma("unroll") \
            for (int m = 0; m < 8; ++m) \
                acc[m][n] = __builtin_amdgcn_mfma_f32_16x16x32_f16(AA[m], WW[n], acc[m][n], 0, 0, 0); \
        __builtin_amdgcn_s_setprio(0); \
    } while (0)

    f32x4 acc[8][8];
#pragma unroll
    for (int m = 0; m < 8; ++m)
#pragma unroll
        for (int n = 0; n < 8; ++n)
            acc[m][n] = (f32x4){0.f, 0.f, 0.f, 0.f};

    half8 aX[8], wX[8], aY[8], wY[8];
    LOADF(aX, wX, 0);

#pragma unroll 1
    for (int t = 0; t < T_STEPS; t += 2) {
        LOADF(aY, wY, t + 1);          // prefetch odd step into Y
        DOMFMA(aX, wX);                // compute even step (waits only on X)
        if (t + 2 < T_STEPS) LOADF(aX, wX, t + 2);   // prefetch next even into X
        DOMFMA(aY, wY);                // compute odd step
    }

    // ---- epilogue: all 4 gates for (r,h) are lane-local (acc[m][g*2+hh]) ----
    float sq_e = sqrtf(noise_e[0]);
    float sq_q = sqrtf(noise_q[0]);
    int hbase = h0 + wn * 32 + fr;
#pragma unroll
    for (int hh = 0; hh < 2; ++hh) {
        int h = hbase + hh * 16;
        float bsum[4];
#pragma unroll
        for (int g = 0; g < 4; ++g)
            bsum[g] = bias_ih[g * 1024 + h] + bias_hh[g * 1024 + h];
#pragma unroll
        for (int m = 0; m < 8; ++m) {
            int r0 = bm0 + wm * 128 + m * 16 + fk * 4;
#pragma unroll
            for (int j = 0; j < 4; ++j) {
                int r = r0 + j;
                float gi = acc[m][0 + hh][j] + bsum[0];
                float gf = acc[m][2 + hh][j] + bsum[1];
                float gc = acc[m][4 + hh][j] + bsum[2];
                float go = acc[m][6 + hh][j] + bsum[3];
                float ig = sigmf(gi), fg = sigmf(gf);
                float cg = tanhfast(gc), og = sigmf(go);
                size_t off = (size_t)r * HDIM + h;
                float cyv = fg * cx[off] + ig * cg + sq_e * eps_c[off];
                float hyv = og * tanhfast(cyv) + sq_q * eps_h[off];
                out[off] = hyv;                                 // hy
                out[(size_t)B_ROWS * HDIM + off] = cyv;         // cy
            }
        }
    }
}

extern "C" void kernel_launch(void* const* d_in, const int* in_sizes, int n_in,
                              void* d_out, int out_size, void* d_ws, size_t ws_size,
                              hipStream_t stream)
{
    const float* input = (const float*)d_in[0];
    const float* hx    = (const float*)d_in[1];
    const float* cx    = (const float*)d_in[2];
    const float* nq    = (const float*)d_in[3];
    const float* ne    = (const float*)d_in[4];
    const float* wih   = (const float*)d_in[5];
    const float* whh   = (const float*)d_in[6];
    const float* bih   = (const float*)d_in[7];
    const float* bhh   = (const float*)d_in[8];
    const float* epsc  = (const float*)d_in[9];
    const float* epsh  = (const float*)d_in[10];
    float* out = (float*)d_out;

    u16* Ap = (u16*)d_ws;
    u16* Wp = Ap + (size_t)B_ROWS * KDIM;   // 32 MB of ws total

    hipLaunchKernelGGL(pack_kernel, dim3(2048), dim3(256), 0, stream,
                       input, hx, wih, whh, Ap, Wp);
    hipLaunchKernelGGL(lstm_fused, dim3(256), dim3(256), 0, stream,
                       Ap, Wp, cx, epsc, epsh, bih, bhh, nq, ne, out);
}

// Round 15
// 103.833 us; speedup vs baseline: 1.7817x; 1.7817x over previous
//
#include <hip/hip_runtime.h>
#include <hip/hip_bf16.h>
#include <cstdint>
#include <cstddef>

// LSTMCell: gates = [input|hx] @ [Wih|Whh]^T + b_ih + b_hh  (4096 x 4096 x K=2048)
// Round 15: R13's no-LDS no-barrier register GEMM (101 us, best), with the per-step
// {12-load burst -> 32-MFMA burst} replaced by 4 rate-matched chunks of
// {3 loads of next step -> 8 MFMAs of current step}, fenced with sched_barrier(0)
// so the compiler can't re-cluster. TA (1536 cyc/step) and MFMA (1242) co-run.
// Wave tile 128x64 (reg-economics cap: ~256 regs/wave at 2 waves/SIMD, R14 spilled).
//
// A layout: [mi(16)][wm(2)][kt(64)][m(8)][lane(64)][8 u16]
// W layout: [hq(16)][wn(4)][kt(64)][g(4)][lane(64)][8 u16]

#define B_ROWS 4096
#define HDIM   1024
#define KDIM   2048
#define BM     256
#define T_STEPS 64

typedef unsigned short u16;
using f32x4  = __attribute__((ext_vector_type(4))) float;
using short8 = __attribute__((ext_vector_type(8))) short;
using half8  = __attribute__((ext_vector_type(8))) _Float16;

__device__ __forceinline__ u16 f2h_bits(float f) {
    _Float16 h = (_Float16)f;                    // v_cvt_f16_f32, RTN
    return __builtin_bit_cast(u16, h);
}

// ---------------- pack: f32 -> f16 fragment-major (same as R13) ----------------
__global__ void pack_kernel(const float* __restrict__ input, const float* __restrict__ hx,
                            const float* __restrict__ wih, const float* __restrict__ whh,
                            u16* __restrict__ Ap, u16* __restrict__ Wp)
{
    const int NA = 16 * 2 * 64 * 8 * 64;   // 1,048,576 16B-groups
    const int NW = 16 * 4 * 64 * 4 * 64;   // 1,048,576
    int stride = gridDim.x * blockDim.x;
    for (int i = blockIdx.x * blockDim.x + threadIdx.x; i < NA + NW; i += stride) {
        int isW = (i >= NA) ? 1 : 0;
        int e = isW ? i - NA : i;
        int lane = e & 63;
        int fr = lane & 15, fk = lane >> 4;
        int kt = isW ? ((e >> 8) & 63) : ((e >> 9) & 63);
        int k  = kt * 32 + fk * 8;
        int row;
        if (isW) {
            int g  = (e >> 6) & 3;
            int wn = (e >> 14) & 3;
            int hqq = e >> 16;
            row = g * 1024 + hqq * 64 + wn * 16 + fr;
        } else {
            int m  = (e >> 6) & 7;
            int wmm = (e >> 15) & 1;
            int mii = e >> 16;
            row = mii * 256 + wmm * 128 + m * 16 + fr;
        }
        const float* s0 = isW ? wih : input;
        const float* s1 = isW ? whh : hx;
        const float* src = (k < 1024) ? (s0 + (size_t)row * 1024 + k)
                                      : (s1 + (size_t)row * 1024 + (k - 1024));
        float4 v0 = *(const float4*)src;
        float4 v1 = *(const float4*)(src + 4);
        u16* dst = (isW ? Wp : Ap) + (size_t)e * 8;
        *(ushort4*)dst = make_ushort4(f2h_bits(v0.x), f2h_bits(v0.y),
                                      f2h_bits(v0.z), f2h_bits(v0.w));
        *(ushort4*)(dst + 4) = make_ushort4(f2h_bits(v1.x), f2h_bits(v1.y),
                                            f2h_bits(v1.z), f2h_bits(v1.w));
    }
}

// ---------------- fused GEMM + LSTM epilogue (no LDS, no barriers) ----------------
__device__ __forceinline__ float sigmf(float x) { return 1.0f / (1.0f + __expf(-x)); }
__device__ __forceinline__ float tanhfast(float x) { return 1.0f - 2.0f / (1.0f + __expf(2.0f * x)); }

__launch_bounds__(512, 1)
__global__ void lstm_fused(const u16* __restrict__ Ap, const u16* __restrict__ Wp,
                           const float* __restrict__ cx, const float* __restrict__ eps_c,
                           const float* __restrict__ eps_h,
                           const float* __restrict__ bias_ih, const float* __restrict__ bias_hh,
                           const float* __restrict__ noise_q, const float* __restrict__ noise_e,
                           float* __restrict__ out)
{
    int bid = blockIdx.x;
    // XCD-bijective swizzle: XCD x gets w in [32x,32x+32) -> 2 hq values
    // (W slice 2 MB packed, L2-resident) x all 16 A panels.
    int w = (bid & 7) * 32 + (bid >> 3);
    int mi = w & 15;          // 16 M-chunks of 256 rows
    int hq = w >> 4;          // 16 h-chunks of 64 cols (x4 gates)
    int bm0 = mi * BM;
    int h0 = hq * 64;

    int tid  = threadIdx.x;
    int lane = tid & 63;
    int wid  = tid >> 6;      // 0..7
    int wm   = wid >> 2;      // M half (128 rows)
    int wn   = wid & 3;       // h quarter (16 cols x 4 gates)
    int fr   = lane & 15, fk = lane >> 4;

    // fragment base pointers (u16 units); strides: A kt=4096, m=512; W kt=2048, g=512
    const u16* pA = Ap + ((size_t)(mi * 2 + wm)) * (64 * 8 * 64 * 8) + lane * 8;
    const u16* pW = Wp + ((size_t)(hq * 4 + wn)) * (64 * 4 * 64 * 8) + lane * 8;

#define LD8(p) __builtin_bit_cast(half8, *(const short8*)(p))
#define SB0()  __builtin_amdgcn_sched_barrier(0)

    // 8 MFMAs: rows mb,mb+1 x all 4 gate-frags of the CURRENT buffer
#define CHUNK8(AA, WW, mb) do { \
        _Pragma("unroll") \
        for (int g = 0; g < 4; ++g) { \
            acc[(mb)][g]     = __builtin_amdgcn_mfma_f32_16x16x32_f16(AA[(mb)],     WW[g], acc[(mb)][g], 0, 0, 0); \
            acc[(mb) + 1][g] = __builtin_amdgcn_mfma_f32_16x16x32_f16(AA[(mb) + 1], WW[g], acc[(mb) + 1][g], 0, 0, 0); \
        } \
    } while (0)

    // One step: compute CUR buffer, trickle-load NXT buffer for step kt_next.
    // Load order: {W0,W1,W2} {W3,A0,A1} {A2,A3,A4} {A5,A6,A7} — next step's chunk0
    // consumers (A0,A1,W0-3) are issued >= 2 chunks before use.
#define STEP(ACUR, WCUR, ANXT, WNXT, kt_next, do_pre) do { \
        const size_t koA = (size_t)(kt_next) * 4096; \
        const size_t koW = (size_t)(kt_next) * 2048; \
        if (do_pre) { WNXT[0] = LD8(pW + koW); WNXT[1] = LD8(pW + koW + 512); \
                      WNXT[2] = LD8(pW + koW + 1024); } \
        SB0(); \
        CHUNK8(ACUR, WCUR, 0); \
        SB0(); \
        if (do_pre) { WNXT[3] = LD8(pW + koW + 1536); \
                      ANXT[0] = LD8(pA + koA); ANXT[1] = LD8(pA + koA + 512); } \
        SB0(); \
        CHUNK8(ACUR, WCUR, 2); \
        SB0(); \
        if (do_pre) { ANXT[2] = LD8(pA + koA + 1024); ANXT[3] = LD8(pA + koA + 1536); \
                      ANXT[4] = LD8(pA + koA + 2048); } \
        SB0(); \
        CHUNK8(ACUR, WCUR, 4); \
        SB0(); \
        if (do_pre) { ANXT[5] = LD8(pA + koA + 2560); ANXT[6] = LD8(pA + koA + 3072); \
                      ANXT[7] = LD8(pA + koA + 3584); } \
        SB0(); \
        CHUNK8(ACUR, WCUR, 6); \
        SB0(); \
    } while (0)

    f32x4 acc[8][4];
#pragma unroll
    for (int m = 0; m < 8; ++m)
#pragma unroll
        for (int g = 0; g < 4; ++g)
            acc[m][g] = (f32x4){0.f, 0.f, 0.f, 0.f};

    half8 aX[8], wX[4], aY[8], wY[4];
#pragma unroll
    for (int m = 0; m < 8; ++m) aX[m] = LD8(pA + m * 512);
#pragma unroll
    for (int g = 0; g < 4; ++g) wX[g] = LD8(pW + g * 512);

#pragma unroll 1
    for (int t = 0; t < T_STEPS; t += 2) {
        STEP(aX, wX, aY, wY, t + 1, true);                    // compute even, load odd
        STEP(aY, wY, aX, wX, t + 2, (t + 2 < T_STEPS));       // compute odd, load next even
    }

    // ---- epilogue: all 4 gates for (r,h) are lane-local ----
    float sq_e = sqrtf(noise_e[0]);
    float sq_q = sqrtf(noise_q[0]);
    int h = h0 + wn * 16 + fr;
    float bsum[4];
#pragma unroll
    for (int g = 0; g < 4; ++g)
        bsum[g] = bias_ih[g * 1024 + h] + bias_hh[g * 1024 + h];
#pragma unroll
    for (int m = 0; m < 8; ++m) {
        int r0 = bm0 + wm * 128 + m * 16 + fk * 4;
#pragma unroll
        for (int j = 0; j < 4; ++j) {
            int r = r0 + j;
            float gi = acc[m][0][j] + bsum[0];
            float gf = acc[m][1][j] + bsum[1];
            float gc = acc[m][2][j] + bsum[2];
            float go = acc[m][3][j] + bsum[3];
            float ig = sigmf(gi), fg = sigmf(gf);
            float cg = tanhfast(gc), og = sigmf(go);
            size_t off = (size_t)r * HDIM + h;
            float cyv = fg * cx[off] + ig * cg + sq_e * eps_c[off];
            float hyv = og * tanhfast(cyv) + sq_q * eps_h[off];
            out[off] = hyv;                                 // hy
            out[(size_t)B_ROWS * HDIM + off] = cyv;         // cy
        }
    }
}

extern "C" void kernel_launch(void* const* d_in, const int* in_sizes, int n_in,
                              void* d_out, int out_size, void* d_ws, size_t ws_size,
                              hipStream_t stream)
{
    const float* input = (const float*)d_in[0];
    const float* hx    = (const float*)d_in[1];
    const float* cx    = (const float*)d_in[2];
    const float* nq    = (const float*)d_in[3];
    const float* ne    = (const float*)d_in[4];
    const float* wih   = (const float*)d_in[5];
    const float* whh   = (const float*)d_in[6];
    const float* bih   = (const float*)d_in[7];
    const float* bhh   = (const float*)d_in[8];
    const float* epsc  = (const float*)d_in[9];
    const float* epsh  = (const float*)d_in[10];
    float* out = (float*)d_out;

    u16* Ap = (u16*)d_ws;
    u16* Wp = Ap + (size_t)B_ROWS * KDIM;   // 32 MB of ws total

    hipLaunchKernelGGL(pack_kernel, dim3(2048), dim3(256), 0, stream,
                       input, hx, wih, whh, Ap, Wp);
    hipLaunchKernelGGL(lstm_fused, dim3(256), dim3(512), 0, stream,
                       Ap, Wp, cx, epsc, epsh, bih, bhh, nq, ne, out);
}